// Round 1
// baseline (539.585 us; speedup 1.0000x reference)
//
#include <hip/hip_runtime.h>

// Fused double-softmax attention, fp32.
// B=4 H=8 S=1024 D=64. Outputs: context [B,H,S,D] then attn [B,H,S,S], fp32.
constexpr int B_ = 4, H_ = 8, S_ = 1024, D_ = 64;
constexpr int BQ = 16;      // q rows per block
constexpr int KT = 128;     // k rows per LDS chunk
constexpr int NT = 512;     // threads per block

__device__ __forceinline__ float wred(float v) {
#pragma unroll
  for (int off = 32; off > 0; off >>= 1) v += __shfl_xor(v, off);
  return v;
}

__global__ __launch_bounds__(NT)
void fused_attn(const float* __restrict__ Q, const float* __restrict__ K,
                const float* __restrict__ V, const int* __restrict__ mask,
                const float* __restrict__ adj, const float* __restrict__ dist,
                const float* __restrict__ cw, const float* __restrict__ cb,
                float* __restrict__ outC, float* __restrict__ outA)
{
  __shared__ float lQ[BQ][D_];            // 4 KB
  __shared__ float lKV[KT][D_ + 4];       // 34.8 KB (pad 4 -> stride 17 f4, conflict-free)
  __shared__ float sc[BQ][S_ + 4];        // 65.8 KB (pad 4 -> bank = (4q+k)%32)
  __shared__ float apart[8][4];           // per-wave partial sums
  __shared__ float rinv1[BQ];
  __shared__ float rinv2[BQ];

  const int tid = threadIdx.x;
  const int qt = blockIdx.x, h = blockIdx.y, b = blockIdx.z;
  const int bh = b * H_ + h;
  const int q0 = qt * BQ;

  const float* Qp = Q + ((size_t)bh * S_ + q0) * D_;
  const float* Kp = K + (size_t)bh * S_ * D_;
  const float* Vp = V + (size_t)bh * S_ * D_;
  const size_t rb = ((size_t)bh * S_ + q0) * S_;   // base into [B,H,S,S] tensors

  // load Q tile (16x64 floats = 256 float4)
  if (tid < BQ * D_ / 4) {
    int q = tid >> 4, d4 = (tid & 15) << 2;
    *reinterpret_cast<float4*>(&lQ[q][d4]) =
        *reinterpret_cast<const float4*>(Qp + q * D_ + d4);
  }
  const float w0 = cw[0], w1 = cw[1], w2 = cw[2], bb = cb[0];

  // ================= Phase A: e = exp(QK^T/8) (masked -> -1 sentinel) =========
  // thread -> (qg = tid>>7 in 0..3 owning q rows 4qg..4qg+3, kk = tid&127)
  const int qg = tid >> 7;
  const int kk = tid & 127;
  const int wave = tid >> 6;
  const int lane = tid & 63;
  float s1p[4] = {0.f, 0.f, 0.f, 0.f};

  for (int kc = 0; kc < S_ / KT; ++kc) {
    __syncthreads();
    // stage K chunk: 128x64 = 2048 float4
#pragma unroll
    for (int i = 0; i < (KT * D_ / 4) / NT; ++i) {
      int f = tid + NT * i;
      int r = f >> 4, d4 = (f & 15) << 2;
      *reinterpret_cast<float4*>(&lKV[r][d4]) =
          *reinterpret_cast<const float4*>(Kp + (size_t)(kc * KT + r) * D_ + d4);
    }
    __syncthreads();

    float acc[4] = {0.f, 0.f, 0.f, 0.f};
#pragma unroll
    for (int d4 = 0; d4 < D_; d4 += 4) {
      float4 kv = *reinterpret_cast<const float4*>(&lKV[kk][d4]);
#pragma unroll
      for (int i = 0; i < 4; ++i) {
        float4 qv = *reinterpret_cast<const float4*>(&lQ[4 * qg + i][d4]);
        acc[i] += qv.x * kv.x + qv.y * kv.y + qv.z * kv.z + qv.w * kv.w;
      }
    }
    const int kglob = kc * KT + kk;
#pragma unroll
    for (int i = 0; i < 4; ++i) {
      const int q = 4 * qg + i;
      const int m = mask[rb + (size_t)q * S_ + kglob];
      float e = __expf(acc[i] * 0.125f);
      if (m) e = -1.f;                 // masked sentinel (ref: exp(NEG-max) == 0)
      sc[q][kglob] = e;
      s1p[i] += m ? 0.f : e;
    }
  }
  // reduce row sums: per-wave shuffle, then combine wave pairs via LDS
#pragma unroll
  for (int i = 0; i < 4; ++i) s1p[i] = wred(s1p[i]);
  if (lane == 0) {
#pragma unroll
    for (int i = 0; i < 4; ++i) apart[wave][i] = s1p[i];
  }
  __syncthreads();
  if (tid < BQ) {
    int g = tid >> 2, qi = tid & 3;
    rinv1[tid] = 1.f / (apart[2 * g][qi] + apart[2 * g + 1][qi]);
  }
  __syncthreads();

  // ================= Phase B: aw = exp(w0*p + w1*dist + w2*adj + b) ===========
  // thread -> (qp = tid>>6 owning rows 2qp,2qp+1 ; kp = tid&63 -> k quads)
  {
    const int qp = tid >> 6, kp = tid & 63;
    const int qa = 2 * qp, qb = 2 * qp + 1;
    const float i1a = rinv1[qa], i1b = rinv1[qb];
    float s2a = 0.f, s2b = 0.f;
    for (int kc = 0; kc < 4; ++kc) {
      const int k4 = kc * 256 + kp * 4;
      {
        float4 e = *reinterpret_cast<const float4*>(&sc[qa][k4]);
        float4 dv = *reinterpret_cast<const float4*>(dist + rb + (size_t)qa * S_ + k4);
        float4 av = *reinterpret_cast<const float4*>(adj + rb + (size_t)qa * S_ + k4);
        float4 aw;
        aw.x = (e.x < 0.f) ? 0.f : __expf(w0 * (e.x * i1a) + w1 * dv.x + w2 * av.x + bb);
        aw.y = (e.y < 0.f) ? 0.f : __expf(w0 * (e.y * i1a) + w1 * dv.y + w2 * av.y + bb);
        aw.z = (e.z < 0.f) ? 0.f : __expf(w0 * (e.z * i1a) + w1 * dv.z + w2 * av.z + bb);
        aw.w = (e.w < 0.f) ? 0.f : __expf(w0 * (e.w * i1a) + w1 * dv.w + w2 * av.w + bb);
        *reinterpret_cast<float4*>(&sc[qa][k4]) = aw;
        s2a += aw.x + aw.y + aw.z + aw.w;
      }
      {
        float4 e = *reinterpret_cast<const float4*>(&sc[qb][k4]);
        float4 dv = *reinterpret_cast<const float4*>(dist + rb + (size_t)qb * S_ + k4);
        float4 av = *reinterpret_cast<const float4*>(adj + rb + (size_t)qb * S_ + k4);
        float4 aw;
        aw.x = (e.x < 0.f) ? 0.f : __expf(w0 * (e.x * i1b) + w1 * dv.x + w2 * av.x + bb);
        aw.y = (e.y < 0.f) ? 0.f : __expf(w0 * (e.y * i1b) + w1 * dv.y + w2 * av.y + bb);
        aw.z = (e.z < 0.f) ? 0.f : __expf(w0 * (e.z * i1b) + w1 * dv.z + w2 * av.z + bb);
        aw.w = (e.w < 0.f) ? 0.f : __expf(w0 * (e.w * i1b) + w1 * dv.w + w2 * av.w + bb);
        *reinterpret_cast<float4*>(&sc[qb][k4]) = aw;
        s2b += aw.x + aw.y + aw.z + aw.w;
      }
    }
    s2a = wred(s2a); s2b = wred(s2b);
    if (lane == 0) { rinv2[qa] = 1.f / s2a; rinv2[qb] = 1.f / s2b; }
    // sync happens at top of phase C chunk loop
  }

  // ================= Phase C: attn write + PV ================================
  // thread -> (kq = tid>>7 k-quarter, qp2 = (tid>>4)&7 q-pair, d4c = (tid&15)*4)
  const int kq = tid >> 7;
  const int qp2 = (tid >> 4) & 7;
  const int d4c = (tid & 15) << 2;
  const int q2a = 2 * qp2, q2b = 2 * qp2 + 1;
  float c0x = 0, c0y = 0, c0z = 0, c0w = 0;
  float c1x = 0, c1y = 0, c1z = 0, c1w = 0;

  for (int kc = 0; kc < S_ / KT; ++kc) {
    __syncthreads();
    // stage V chunk
#pragma unroll
    for (int i = 0; i < (KT * D_ / 4) / NT; ++i) {
      int f = tid + NT * i;
      int r = f >> 4, d4 = (f & 15) << 2;
      *reinterpret_cast<float4*>(&lKV[r][d4]) =
          *reinterpret_cast<const float4*>(Vp + (size_t)(kc * KT + r) * D_ + d4);
    }
    __syncthreads();
    // write normalized attn for this chunk (2048 values, 4 per thread)
#pragma unroll
    for (int i = 0; i < 4; ++i) {
      int f = tid + NT * i;
      int q = f >> 7, kx = f & 127;
      float aw = sc[q][kc * KT + kx];
      outA[rb + (size_t)q * S_ + kc * KT + kx] = aw * rinv2[q];
    }
    // PV accumulate over this chunk's quarter
#pragma unroll
    for (int k = 0; k < KT / 4; ++k) {
      const int kx = kq * (KT / 4) + k;
      float4 v = *reinterpret_cast<const float4*>(&lKV[kx][d4c]);
      float p0 = sc[q2a][kc * KT + kx];
      float p1 = sc[q2b][kc * KT + kx];
      c0x += p0 * v.x; c0y += p0 * v.y; c0z += p0 * v.z; c0w += p0 * v.w;
      c1x += p1 * v.x; c1y += p1 * v.y; c1z += p1 * v.z; c1w += p1 * v.w;
    }
  }
  __syncthreads();
  // cross-thread reduce over kq quarters (scratch reuses sc)
  float* scratch = &sc[0][0];
  {
    float* p = scratch + (size_t)tid * 8;
    p[0] = c0x; p[1] = c0y; p[2] = c0z; p[3] = c0w;
    p[4] = c1x; p[5] = c1y; p[6] = c1z; p[7] = c1w;
  }
  __syncthreads();
  if (kq == 0) {
#pragma unroll
    for (int m = 1; m < 4; ++m) {
      const float* p = scratch + (size_t)(tid + 128 * m) * 8;
      c0x += p[0]; c0y += p[1]; c0z += p[2]; c0w += p[3];
      c1x += p[4]; c1y += p[5]; c1z += p[6]; c1w += p[7];
    }
    const float i2a = rinv2[q2a], i2b = rinv2[q2b];
    float4 o0 = make_float4(c0x * i2a, c0y * i2a, c0z * i2a, c0w * i2a);
    float4 o1 = make_float4(c1x * i2b, c1y * i2b, c1z * i2b, c1w * i2b);
    *reinterpret_cast<float4*>(outC + ((size_t)bh * S_ + q0 + q2a) * D_ + d4c) = o0;
    *reinterpret_cast<float4*>(outC + ((size_t)bh * S_ + q0 + q2b) * D_ + d4c) = o1;
  }
}

extern "C" void kernel_launch(void* const* d_in, const int* in_sizes, int n_in,
                              void* d_out, int out_size, void* d_ws, size_t ws_size,
                              hipStream_t stream) {
  const float* Q    = (const float*)d_in[0];
  const float* K    = (const float*)d_in[1];
  const float* V    = (const float*)d_in[2];
  const int*   mask = (const int*)  d_in[3];   // bool -> int32 per harness convention
  const float* adj  = (const float*)d_in[4];
  const float* dist = (const float*)d_in[5];
  const float* cw   = (const float*)d_in[6];
  const float* cb   = (const float*)d_in[7];

  float* outC = (float*)d_out;                                   // [B,H,S,D]
  float* outA = outC + (size_t)B_ * H_ * S_ * D_;                // [B,H,S,S]

  dim3 grid(S_ / BQ, H_, B_);
  fused_attn<<<grid, NT, 0, stream>>>(Q, K, V, mask, adj, dist, cw, cb, outC, outA);
}